// Round 4
// baseline (401.993 us; speedup 1.0000x reference)
//
#include <hip/hip_runtime.h>
#include <stdint.h>

#define NB 512
#define SL 1024
#define NT 64

typedef float v2f __attribute__((ext_vector_type(2)));
typedef unsigned int v2u __attribute__((ext_vector_type(2)));
typedef float v4f __attribute__((ext_vector_type(4)));

__device__ __forceinline__ float wave_max6(float v) {
    #pragma unroll
    for (int off = 32; off >= 1; off >>= 1)
        v = fmaxf(v, __shfl_xor(v, off, 64));
    return v;
}
__device__ __forceinline__ float wave_sum_f(float v) {
    #pragma unroll
    for (int off = 32; off >= 1; off >>= 1)
        v += __shfl_xor(v, off, 64);
    return v;
}

// One block (= one wave) per batch row: gold score + forward scan in
// scaled-exp fp32 domain. The per-step 64-wide broadcast of the state vector
// goes through the SCALAR register file (v_readlane -> sgpr pair ->
// v_pk_fma_f32), not LDS: no DS-pipe latency on the chain and no DS
// interference from the co-resident wave on the same CU.
__global__ void __launch_bounds__(64) crf_fused_kernel(
    const int* __restrict__ tags, const void* __restrict__ mask,
    const float* __restrict__ emit, const float* __restrict__ trans,
    float* __restrict__ out)
{
    const int b = blockIdx.x;
    const int lane = threadIdx.x;
    const float* erow = emit + (size_t)b * SL * NT;
    const int* trow = tags + b * SL;

    // ---------- phase 0: gold-path score + length ----------
    const unsigned char* mb = (const unsigned char*)mask;
    const bool mask_is_i32 = ((mb[1] | mb[2] | mb[3]) == 0);  // dtype sniff

    float acc = 0.f; int cnt = 0;
    #pragma unroll
    for (int j = 0; j < 16; ++j) {
        const int i = lane + 64 * j;
        const int mk = mask_is_i32 ? (((const int*)mask)[(size_t)b * SL + i] != 0)
                                   : (mb[(size_t)b * SL + i] != 0);
        if (mk) {
            const int tg = trow[i];
            float val = erow[(size_t)i * NT + tg];
            if (i > 0) val += trans[trow[i - 1] * NT + tg];
            acc += val; cnt += 1;
        }
    }
    #pragma unroll
    for (int off = 32; off >= 1; off >>= 1) {
        acc += __shfl_xor(acc, off, 64);
        cnt += __shfl_xor(cnt, off, 64);
    }
    const float ts = acc;
    const int len = cnt;

    // ---------- phase 1: forward scan ----------
    // E2[k] = { exp(trans[2k][lane]), exp(trans[2k+1][lane]) } : this lane's
    // column of exp(transition), fp32, packed as vgpr pairs for v_pk_fma_f32.
    v2f E2[NT / 2];
    #pragma unroll
    for (int k = 0; k < NT / 2; ++k) {
        E2[k].x = __expf(trans[(2 * k + 0) * NT + lane]);
        E2[k].y = __expf(trans[(2 * k + 1) * NT + lane]);
    }

    float d0 = erow[lane];
    float m0 = wave_max6(d0);
    float v = __expf(d0 - m0);
    float logacc = m0;

    // One scan step: v'[t] = (sum_p v[p]*E[p][t]) * EX,  EX = exp(emit).
    // Broadcast via readlane: sp = {v[2k], v[2k+1]} lands in an sgpr pair,
    // consumed as the single scalar operand of v_pk_fma_f32.
#define STEP(EX)                                                           \
    {                                                                      \
        const int vb_ = __float_as_int(v);                                 \
        v2f a0 = {0.f, 0.f}, a1 = {0.f, 0.f};                              \
        v2f a2 = {0.f, 0.f}, a3 = {0.f, 0.f};                              \
        _Pragma("unroll")                                                  \
        for (int k = 0; k < 8; ++k) {                                      \
            v2u s0, s1, s2, s3;                                            \
            s0.x = (unsigned)__builtin_amdgcn_readlane(vb_, 8 * k + 0);    \
            s0.y = (unsigned)__builtin_amdgcn_readlane(vb_, 8 * k + 1);    \
            s1.x = (unsigned)__builtin_amdgcn_readlane(vb_, 8 * k + 2);    \
            s1.y = (unsigned)__builtin_amdgcn_readlane(vb_, 8 * k + 3);    \
            s2.x = (unsigned)__builtin_amdgcn_readlane(vb_, 8 * k + 4);    \
            s2.y = (unsigned)__builtin_amdgcn_readlane(vb_, 8 * k + 5);    \
            s3.x = (unsigned)__builtin_amdgcn_readlane(vb_, 8 * k + 6);    \
            s3.y = (unsigned)__builtin_amdgcn_readlane(vb_, 8 * k + 7);    \
            asm("v_pk_fma_f32 %0, %1, %2, %0"                              \
                : "+v"(a0) : "s"(s0), "v"(E2[4 * k + 0]));                 \
            asm("v_pk_fma_f32 %0, %1, %2, %0"                              \
                : "+v"(a1) : "s"(s1), "v"(E2[4 * k + 1]));                 \
            asm("v_pk_fma_f32 %0, %1, %2, %0"                              \
                : "+v"(a2) : "s"(s2), "v"(E2[4 * k + 2]));                 \
            asm("v_pk_fma_f32 %0, %1, %2, %0"                              \
                : "+v"(a3) : "s"(s3), "v"(E2[4 * k + 3]));                 \
        }                                                                  \
        v2f h = (a0 + a1) + (a2 + a3);                                     \
        v = (h.x + h.y) * (EX);                                            \
    }

    const int nstep = len - 1;     // steps i = 1 .. len-1
    const int ngrp = nstep >> 2;   // groups of 4
    int i = 1;

    v4f emq;
    if (ngrp > 0) {
        emq.x = erow[(i + 0) * NT + lane];
        emq.y = erow[(i + 1) * NT + lane];
        emq.z = erow[(i + 2) * NT + lane];
        emq.w = erow[(i + 3) * NT + lane];
    }
    for (int g = 0; g < ngrp; ++g) {
        // emission exps are independent of the chain: issue first
        float ex0 = __expf(emq.x), ex1 = __expf(emq.y);
        float ex2 = __expf(emq.z), ex3 = __expf(emq.w);
        const int ip = i + 4;
        if (g + 1 < ngrp) {  // prefetch next group's emissions
            emq.x = erow[(ip + 0) * NT + lane];
            emq.y = erow[(ip + 1) * NT + lane];
            emq.z = erow[(ip + 2) * NT + lane];
            emq.w = erow[(ip + 3) * NT + lane];
        }
        STEP(ex0)
        STEP(ex1)
        STEP(ex2)
        STEP(ex3)
        // renorm: exact power-of-2 rescale; any lane's exponent is a safe
        // wave-uniform scale (inter-lane spread bounded by the transition
        // dynamic range; 4-step growth stays far inside fp32).
        {
            uint32_t sb = __builtin_amdgcn_readfirstlane(__float_as_uint(v));
            int ex = (int)((sb >> 23) & 0xffu);
            v *= __uint_as_float((uint32_t)(254 - ex) << 23);  // 2^(127-ex)
            logacc += (float)(ex - 127) * 0.69314718055994530942f;
        }
        i += 4;
    }
    for (; i < len; ++i) {  // remainder (<=3 steps)
        float e = __expf(erow[i * NT + lane]);
        STEP(e)
    }
#undef STEP

    float sum = wave_sum_f(v);
    float log_z = logacc + __logf(sum);
    if (lane == 0) out[b] = -(ts - log_z);
}

extern "C" void kernel_launch(void* const* d_in, const int* in_sizes, int n_in,
                              void* d_out, int out_size, void* d_ws, size_t ws_size,
                              hipStream_t stream) {
    (void)in_sizes; (void)n_in; (void)out_size; (void)d_ws; (void)ws_size;
    const int*   tags  = (const int*)d_in[0];
    const void*  mask  = d_in[1];
    const float* emit  = (const float*)d_in[2];
    const float* trans = (const float*)d_in[3];
    float* out = (float*)d_out;

    crf_fused_kernel<<<dim3(NB), dim3(64), 0, stream>>>(tags, mask, emit, trans, out);
}